// Round 4
// baseline (136.609 us; speedup 1.0000x reference)
//
#include <hip/hip_runtime.h>
#include <hip/hip_bf16.h>
#include <stdint.h>

#define N_ROWS 8192
#define DIM    1024
#define INV_T  14.2857142857142857f   // 1/0.07

#define BM 128
#define BK 64
#define NTILE  (N_ROWS / BM)     // 64
#define NSLICE (2 * NTILE)       // 128 col-slices of 64
#define NKT    (DIM / BK)        // 16 K-tiles

typedef __bf16 bf16x8 __attribute__((ext_vector_type(8)));
typedef float  f32x4  __attribute__((ext_vector_type(4)));

__device__ __forceinline__ unsigned short f2bf(float x) {
    __hip_bfloat16 h = __float2bfloat16(x);
    return *reinterpret_cast<unsigned short*>(&h);
}

// ---------------- kernel 1: row-normalize f32 -> bf16 ----------------
__global__ __launch_bounds__(256) void norm_kernel(
    const float* __restrict__ V, unsigned short* __restrict__ A)
{
    const int row  = blockIdx.x;
    const int tid  = threadIdx.x;
    const int lane = tid & 63, wid = tid >> 6;

    const float4* vp = (const float4*)(V + (size_t)row * DIM);
    float4 v = vp[tid];
    float ss = v.x*v.x + v.y*v.y + v.z*v.z + v.w*v.w;
    #pragma unroll
    for (int off = 32; off > 0; off >>= 1) ss += __shfl_down(ss, off, 64);

    __shared__ float wsum[4];
    if (lane == 0) wsum[wid] = ss;
    __syncthreads();
    const float inv = 1.0f / sqrtf(wsum[0] + wsum[1] + wsum[2] + wsum[3]);

    ushort4 o;
    o.x = f2bf(v.x * inv);
    o.y = f2bf(v.y * inv);
    o.z = f2bf(v.z * inv);
    o.w = f2bf(v.w * inv);
    *(ushort4*)(A + (size_t)row * DIM + tid * 4) = o;
}

// ---- wait / barrier helpers (raw: no vmcnt-0 drain like __syncthreads) ----
#define LGKM0() do { asm volatile("s_waitcnt lgkmcnt(0)" ::: "memory"); \
                     __builtin_amdgcn_sched_barrier(0); } while (0)
#define BAR()   do { __builtin_amdgcn_s_barrier(); \
                     asm volatile("" ::: "memory"); } while (0)

// ---------------- kernel 2: fused symmetric sim GEMM + epilogue ----------------
// 1-D grid of 2112 = 64 x 33 pairs, XCD-swizzled (each XCD gets a contiguous
// rt-range: 2112/8 = 264 = 8 rt x 33 ctl). Pair {rt, ct=(rt+ctl)&63};
// ctl==32 valid only for rt<32. Double-buffered LDS, counted-vmcnt pipeline:
// per K-tile two MFMA phases; prefetch of tile kt+2 stays in flight across
// the barriers (vmcnt(8), never 0 in main loop).
__global__ __launch_bounds__(256, 2) void sim_kernel(
    const unsigned short* __restrict__ A, const int* __restrict__ labels,
    float* __restrict__ psum, float* __restrict__ ppos, float* __restrict__ pcnt)
{
    __shared__ __align__(16) unsigned short As[2][BM * BK];
    __shared__ __align__(16) unsigned short Bs[2][BM * BK];

    const int bid = blockIdx.x;
    const int p   = (bid & 7) * 264 + (bid >> 3);   // bijective XCD swizzle
    const int rt  = p / 33;
    const int ctl = p % 33;
    if (ctl == 32 && rt >= 32) return;              // uniform: whole block exits
    const int  ct     = (rt + ctl) & (NTILE - 1);
    const bool isDiag = (ctl == 0);

    const int tid  = threadIdx.x;
    const int lane = tid & 63;
    const int wid  = tid >> 6;
    const int wr   = wid >> 1;      // wave row 0..1
    const int wc   = wid & 1;       // wave col 0..1

    const int rbase = rt * BM;
    const int cbase = ct * BM;

    const int rowq = rbase + wr * 64 + ((lane >> 4) << 2);
    const int col0 = cbase + wc * 64 + (lane & 15);

    int labr[16];
    #pragma unroll
    for (int m = 0; m < 4; ++m)
        #pragma unroll
        for (int r = 0; r < 4; ++r)
            labr[m * 4 + r] = labels[rowq + m * 16 + r];
    int labc[4];
    #pragma unroll
    for (int n = 0; n < 4; ++n) labc[n] = labels[col0 + n * 16];

    f32x4 acc[4][4];
    #pragma unroll
    for (int m = 0; m < 4; ++m)
        #pragma unroll
        for (int n = 0; n < 4; ++n)
            acc[m][n] = (f32x4){0.f, 0.f, 0.f, 0.f};

    // staging: linear LDS dest (global_load_lds), source chunk XOR-swizzled;
    // read side applies the same XOR (rule 21 pair). 8 VMEM instrs per call.
    #define STAGE(buf, kt)                                                         \
    {                                                                              \
        const int kbase = (kt) * BK;                                               \
        _Pragma("unroll")                                                          \
        for (int i = 0; i < 4; ++i) {                                              \
            const int c    = i * 256 + tid;                                        \
            const int rowc = c >> 3;                                               \
            const int kcs  = (c & 7) ^ (rowc & 7);                                 \
            const unsigned short* gA = A + (size_t)(rbase + rowc) * DIM + kbase + kcs * 8; \
            const unsigned short* gB = A + (size_t)(cbase + rowc) * DIM + kbase + kcs * 8; \
            const int ldsOff = i * 4096 + wid * 1024;   /* +lane*16 by HW */       \
            __builtin_amdgcn_global_load_lds(                                      \
                (const __attribute__((address_space(1))) void*)gA,                 \
                (__attribute__((address_space(3))) void*)((char*)As[buf] + ldsOff),\
                16, 0, 0);                                                         \
            __builtin_amdgcn_global_load_lds(                                      \
                (const __attribute__((address_space(1))) void*)gB,                 \
                (__attribute__((address_space(3))) void*)((char*)Bs[buf] + ldsOff),\
                16, 0, 0);                                                         \
        }                                                                          \
    }

    // prologue: stage tiles 0 and 1; drain tile 0 only (tile 1 stays in flight)
    STAGE(0, 0);
    STAGE(1, 1);
    asm volatile("s_waitcnt vmcnt(8)" ::: "memory");
    BAR();

    for (int kt = 0; kt < NKT; ++kt) {
        const int cur = kt & 1;

        // ---- phase 0: read all B frags (held) + A m0,m1; 16 MFMA
        bf16x8 bfr[4][2];
        #pragma unroll
        for (int n = 0; n < 4; ++n)
            #pragma unroll
            for (int ks = 0; ks < 2; ++ks) {
                const int rowb = wc * 64 + n * 16 + (lane & 15);
                const int kd0  = ks * 4 + (lane >> 4);
                bfr[n][ks] = *(const bf16x8*)&Bs[cur][rowb * BK + ((kd0 ^ (rowb & 7)) << 3)];
            }
        bf16x8 af0[2][2];
        #pragma unroll
        for (int m = 0; m < 2; ++m)
            #pragma unroll
            for (int ks = 0; ks < 2; ++ks) {
                const int rowa = wr * 64 + m * 16 + (lane & 15);
                const int kd0  = ks * 4 + (lane >> 4);
                af0[m][ks] = *(const bf16x8*)&As[cur][rowa * BK + ((kd0 ^ (rowa & 7)) << 3)];
            }
        LGKM0();
        __builtin_amdgcn_s_setprio(1);
        #pragma unroll
        for (int m = 0; m < 2; ++m)
            #pragma unroll
            for (int n = 0; n < 4; ++n)
                #pragma unroll
                for (int ks = 0; ks < 2; ++ks)
                    acc[m][n] = __builtin_amdgcn_mfma_f32_16x16x32_bf16(
                        af0[m][ks], bfr[n][ks], acc[m][n], 0, 0, 0);
        __builtin_amdgcn_s_setprio(0);

        // ---- phase 1: read A m2,m3; close reads; stage kt+2; 16 MFMA
        bf16x8 af1[2][2];
        #pragma unroll
        for (int m = 0; m < 2; ++m)
            #pragma unroll
            for (int ks = 0; ks < 2; ++ks) {
                const int rowa = wr * 64 + (m + 2) * 16 + (lane & 15);
                const int kd0  = ks * 4 + (lane >> 4);
                af1[m][ks] = *(const bf16x8*)&As[cur][rowa * BK + ((kd0 ^ (rowa & 7)) << 3)];
            }
        LGKM0();
        BAR();                              // all waves' reads of buf cur done
        if (kt < NKT - 2) STAGE(cur, kt + 2);   // refill freed buffer

        __builtin_amdgcn_s_setprio(1);
        #pragma unroll
        for (int m = 0; m < 2; ++m)
            #pragma unroll
            for (int n = 0; n < 4; ++n)
                #pragma unroll
                for (int ks = 0; ks < 2; ++ks)
                    acc[m + 2][n] = __builtin_amdgcn_mfma_f32_16x16x32_bf16(
                        af1[m][ks], bfr[n][ks], acc[m + 2][n], 0, 0, 0);
        __builtin_amdgcn_s_setprio(0);

        // drain tile kt+1's 8 loads; keep kt+2's 8 in flight (never vmcnt 0)
        if (kt < NKT - 2)       { asm volatile("s_waitcnt vmcnt(8)" ::: "memory"); }
        else if (kt == NKT - 2) { asm volatile("s_waitcnt vmcnt(0)" ::: "memory"); }
        if (kt < NKT - 1) BAR();            // next tile resident for all waves
    }

    // ---------------- epilogue ----------------
    float sum_p[16], pos_p[16], cnt_p[16];
    #pragma unroll
    for (int i = 0; i < 16; ++i) { sum_p[i] = 0.f; pos_p[i] = 0.f; cnt_p[i] = 0.f; }
    float csum[4], cpos[4], ccnt[4];
    #pragma unroll
    for (int n = 0; n < 4; ++n) { csum[n] = 0.f; cpos[n] = 0.f; ccnt[n] = 0.f; }

    if (isDiag) {
        #pragma unroll
        for (int m = 0; m < 4; ++m)
            #pragma unroll
            for (int n = 0; n < 4; ++n) {
                const int gcol = col0 + n * 16;
                #pragma unroll
                for (int r = 0; r < 4; ++r) {
                    const float s    = acc[m][n][r] * INV_T;
                    const int   i16  = m * 4 + r;
                    const int   grow = rowq + m * 16 + r;
                    const bool  diag = (grow == gcol);
                    sum_p[i16] += diag ? 0.f : __expf(s);
                    if ((labr[i16] == labc[n]) && !diag) {
                        pos_p[i16] += s; cnt_p[i16] += 1.f;
                    }
                }
            }
    } else {
        #pragma unroll
        for (int m = 0; m < 4; ++m)
            #pragma unroll
            for (int n = 0; n < 4; ++n) {
                #pragma unroll
                for (int r = 0; r < 4; ++r) {
                    const float s   = acc[m][n][r] * INV_T;
                    const int   i16 = m * 4 + r;
                    const float e   = __expf(s);
                    sum_p[i16] += e;
                    csum[n]    += e;
                    if (labr[i16] == labc[n]) {
                        pos_p[i16] += s; cnt_p[i16] += 1.f;
                        cpos[n]    += s; ccnt[n]    += 1.f;
                    }
                }
            }
    }

    // row-side: reduce across the 16 lanes sharing each row -> slice ct*2+wc
    #pragma unroll
    for (int i = 0; i < 16; ++i) {
        float se = sum_p[i], pp = pos_p[i], cc = cnt_p[i];
        #pragma unroll
        for (int off = 1; off < 16; off <<= 1) {
            se += __shfl_xor(se, off, 16);
            pp += __shfl_xor(pp, off, 16);
            cc += __shfl_xor(cc, off, 16);
        }
        if ((lane & 15) == 0) {
            const int row = rowq + (i >> 2) * 16 + (i & 3);
            const size_t idx = (size_t)row * NSLICE + ct * 2 + wc;
            psum[idx] = se;
            ppos[idx] = pp;
            pcnt[idx] = cc;
        }
    }

    // col-side (off-diag only): reduce across 4 lane-groups -> slice rt*2+wr
    if (!isDiag) {
        #pragma unroll
        for (int n = 0; n < 4; ++n) {
            float se = csum[n], pp = cpos[n], cc = ccnt[n];
            se += __shfl_xor(se, 16, 64); se += __shfl_xor(se, 32, 64);
            pp += __shfl_xor(pp, 16, 64); pp += __shfl_xor(pp, 32, 64);
            cc += __shfl_xor(cc, 16, 64); cc += __shfl_xor(cc, 32, 64);
            if (lane < 16) {
                const int gcol = col0 + n * 16;
                const size_t idx = (size_t)gcol * NSLICE + rt * 2 + wr;
                psum[idx] = se;
                ppos[idx] = pp;
                pcnt[idx] = cc;
            }
        }
    }
}

// ---------------- kernel 3a: per-row reduce over 128 slices ----------------
__global__ __launch_bounds__(128) void finalize1_kernel(
    const float* __restrict__ psum, const float* __restrict__ ppos,
    const float* __restrict__ pcnt, float* __restrict__ bpart)
{
    const int row  = blockIdx.x * 128 + threadIdx.x;
    const int lane = threadIdx.x & 63, wid = threadIdx.x >> 6;

    const float4* vs = (const float4*)(psum + (size_t)row * NSLICE);
    const float4* vp = (const float4*)(ppos + (size_t)row * NSLICE);
    const float4* vc = (const float4*)(pcnt + (size_t)row * NSLICE);
    float s = 0.f, p = 0.f, c = 0.f;
    #pragma unroll
    for (int i = 0; i < NSLICE / 4; ++i) {
        float4 a = vs[i]; s += a.x + a.y + a.z + a.w;
        float4 b = vp[i]; p += b.x + b.y + b.z + b.w;
        float4 d = vc[i]; c += d.x + d.y + d.z + d.w;
    }
    float per = (c > 0.f) ? (logf(s) - p / c) : 0.f;
    #pragma unroll
    for (int off = 32; off > 0; off >>= 1) per += __shfl_down(per, off, 64);
    __shared__ float w2[2];
    if (lane == 0) w2[wid] = per;
    __syncthreads();
    if (threadIdx.x == 0) bpart[blockIdx.x] = w2[0] + w2[1];
}

// ---------------- kernel 3b: final 64-way sum ----------------
__global__ __launch_bounds__(64) void finalize2_kernel(
    const float* __restrict__ bpart, float* __restrict__ out)
{
    const int lane = threadIdx.x;
    float v = bpart[lane];
    #pragma unroll
    for (int off = 32; off > 0; off >>= 1) v += __shfl_down(v, off, 64);
    if (lane == 0) out[0] = v;
}

extern "C" void kernel_launch(void* const* d_in, const int* in_sizes, int n_in,
                              void* d_out, int out_size, void* d_ws, size_t ws_size,
                              hipStream_t stream) {
    const float* V      = (const float*)d_in[0];
    const int*   labels = (const int*)d_in[1];
    float*       out    = (float*)d_out;

    // ws layout: Abf 16 MB | psum 4 MB | ppos 4 MB | pcnt 4 MB | bpart 256 B
    unsigned short* Abf = (unsigned short*)d_ws;
    char* base = (char*)d_ws + (size_t)N_ROWS * DIM * 2;
    float* psum  = (float*)(base);
    float* ppos  = (float*)(base + (size_t)N_ROWS * NSLICE * 4);
    float* pcnt  = (float*)(base + (size_t)N_ROWS * NSLICE * 8);
    float* bpart = (float*)(base + (size_t)N_ROWS * NSLICE * 12);

    norm_kernel<<<N_ROWS, 256, 0, stream>>>(V, Abf);
    sim_kernel<<<NTILE * (NTILE / 2 + 1), 256, 0, stream>>>(Abf, labels, psum, ppos, pcnt);
    finalize1_kernel<<<N_ROWS / 128, 128, 0, stream>>>(psum, ppos, pcnt, bpart);
    finalize2_kernel<<<1, 64, 0, stream>>>(bpart, out);
}

// Round 5
// 102.096 us; speedup vs baseline: 1.3380x; 1.3380x over previous
//
#include <hip/hip_runtime.h>
#include <hip/hip_bf16.h>
#include <stdint.h>

#define N_ROWS 8192
#define DIM    1024
#define INV_T  14.2857142857142857f   // 1/0.07

#define BM  128
#define BKB 128                  // K-bytes per LDS tile (fp8: 128 k-elements)
#define NTILE  (N_ROWS / BM)     // 64
#define NSLICE (2 * NTILE)       // 128 col-slices of 64
#define NKT    (DIM / BKB)       // 8 K-tiles

typedef int   i32x4 __attribute__((ext_vector_type(4)));
typedef int   i32x8 __attribute__((ext_vector_type(8)));
typedef float f32x4 __attribute__((ext_vector_type(4)));

// ---------------- kernel 1: row-normalize f32 -> fp8 e4m3 (OCP) ----------------
__global__ __launch_bounds__(256) void norm_kernel(
    const float* __restrict__ V, unsigned char* __restrict__ A8)
{
    const int row  = blockIdx.x;
    const int tid  = threadIdx.x;
    const int lane = tid & 63, wid = tid >> 6;

    const float4* vp = (const float4*)(V + (size_t)row * DIM);
    float4 v = vp[tid];
    float ss = v.x*v.x + v.y*v.y + v.z*v.z + v.w*v.w;
    #pragma unroll
    for (int off = 32; off > 0; off >>= 1) ss += __shfl_down(ss, off, 64);

    __shared__ float wsum[4];
    if (lane == 0) wsum[wid] = ss;
    __syncthreads();
    const float inv = 1.0f / sqrtf(wsum[0] + wsum[1] + wsum[2] + wsum[3]);

    // pack 4 normalized floats -> 4 OCP e4m3 bytes (gfx950 HW cvt is OCP)
    int pk = __builtin_amdgcn_cvt_pk_fp8_f32(v.x * inv, v.y * inv, 0,  false);
    pk     = __builtin_amdgcn_cvt_pk_fp8_f32(v.z * inv, v.w * inv, pk, true);
    ((int*)(A8 + (size_t)row * DIM))[tid] = pk;
}

// ---------------- kernel 2: fused symmetric sim GEMM (MX-fp8) + epilogue ----------------
// grid (64, 33): block = unordered tile pair {rt, ct=(rt+ctl)&63}; ctl==0 diag;
// ctl==32 valid only for rt<32. R3's proven single-buffer 2-barrier shell.
// MFMA: mfma_scale_f32_16x16x128_f8f6f4, scale fixed at 0x7F (=2^0, exact 1.0).
// Partials: partial[row][slice]; each (row,slice) written by exactly one wave.
__global__ __launch_bounds__(256, 3) void sim_kernel(
    const unsigned char* __restrict__ A8, const int* __restrict__ labels,
    float* __restrict__ psum, float* __restrict__ ppos, float* __restrict__ pcnt)
{
    __shared__ __align__(16) unsigned char As[BM * BKB];   // 16 KB
    __shared__ __align__(16) unsigned char Bs[BM * BKB];   // 16 KB

    const int rt  = blockIdx.x;
    const int ctl = blockIdx.y;
    if (ctl == NTILE / 2 && rt >= NTILE / 2) return;       // uniform exit
    const int  ct     = (rt + ctl) & (NTILE - 1);
    const bool isDiag = (ctl == 0);

    const int tid  = threadIdx.x;
    const int lane = tid & 63;
    const int wid  = tid >> 6;
    const int wr   = wid >> 1;      // wave row 0..1
    const int wc   = wid & 1;       // wave col 0..1

    const int rbase = rt * BM;
    const int cbase = ct * BM;

    const int rowq = rbase + wr * 64 + ((lane >> 4) << 2);
    const int col0 = cbase + wc * 64 + (lane & 15);

    int labr[16];
    #pragma unroll
    for (int m = 0; m < 4; ++m)
        #pragma unroll
        for (int r = 0; r < 4; ++r)
            labr[m * 4 + r] = labels[rowq + m * 16 + r];
    int labc[4];
    #pragma unroll
    for (int n = 0; n < 4; ++n) labc[n] = labels[col0 + n * 16];

    f32x4 acc[4][4];
    #pragma unroll
    for (int m = 0; m < 4; ++m)
        #pragma unroll
        for (int n = 0; n < 4; ++n)
            acc[m][n] = (f32x4){0.f, 0.f, 0.f, 0.f};

    // staging: linear LDS dest; source 16B-chunk XOR-swizzled (^row&7), read
    // side applies the same XOR (rule 21 involution pair). 8 rows/1KB step:
    // lds byte o -> row o>>7, chunk (o>>4)&7; matches c = i*256+tid mapping.
    #define STAGE(kt)                                                              \
    {                                                                              \
        const int kbase = (kt) * BKB;                                              \
        _Pragma("unroll")                                                          \
        for (int i = 0; i < 4; ++i) {                                              \
            const int c    = i * 256 + tid;                                        \
            const int rowc = c >> 3;                                               \
            const int kcs  = (c & 7) ^ (rowc & 7);                                 \
            const unsigned char* gA = A8 + (size_t)(rbase + rowc) * DIM + kbase + kcs * 16; \
            const unsigned char* gB = A8 + (size_t)(cbase + rowc) * DIM + kbase + kcs * 16; \
            const int ldsOff = i * 4096 + wid * 1024;   /* +lane*16 by HW */       \
            __builtin_amdgcn_global_load_lds(                                      \
                (const __attribute__((address_space(1))) void*)gA,                 \
                (__attribute__((address_space(3))) void*)(As + ldsOff),            \
                16, 0, 0);                                                         \
            __builtin_amdgcn_global_load_lds(                                      \
                (const __attribute__((address_space(1))) void*)gB,                 \
                (__attribute__((address_space(3))) void*)(Bs + ldsOff),            \
                16, 0, 0);                                                         \
        }                                                                          \
    }

    const int t = lane >> 4;        // K-block 0..3 (32 k-bytes each)

    for (int kt = 0; kt < NKT; ++kt) {
        STAGE(kt);
        __syncthreads();            // drains vmcnt(0): tiles resident

        i32x8 a8[4], b8[4];
        #pragma unroll
        for (int m = 0; m < 4; ++m) {
            const int rowa = wr * 64 + m * 16 + (lane & 15);
            const int c0 = ((2 * t)     ^ (rowa & 7)) << 4;
            const int c1 = ((2 * t + 1) ^ (rowa & 7)) << 4;
            i32x4 lo = *(const i32x4*)(As + rowa * BKB + c0);
            i32x4 hi = *(const i32x4*)(As + rowa * BKB + c1);
            i32x8 f; f[0]=lo[0]; f[1]=lo[1]; f[2]=lo[2]; f[3]=lo[3];
                     f[4]=hi[0]; f[5]=hi[1]; f[6]=hi[2]; f[7]=hi[3];
            a8[m] = f;
        }
        #pragma unroll
        for (int n = 0; n < 4; ++n) {
            const int rowb = wc * 64 + n * 16 + (lane & 15);
            const int c0 = ((2 * t)     ^ (rowb & 7)) << 4;
            const int c1 = ((2 * t + 1) ^ (rowb & 7)) << 4;
            i32x4 lo = *(const i32x4*)(Bs + rowb * BKB + c0);
            i32x4 hi = *(const i32x4*)(Bs + rowb * BKB + c1);
            i32x8 f; f[0]=lo[0]; f[1]=lo[1]; f[2]=lo[2]; f[3]=lo[3];
                     f[4]=hi[0]; f[5]=hi[1]; f[6]=hi[2]; f[7]=hi[3];
            b8[n] = f;
        }

        #pragma unroll
        for (int m = 0; m < 4; ++m)
            #pragma unroll
            for (int n = 0; n < 4; ++n)
                acc[m][n] = __builtin_amdgcn_mfma_scale_f32_16x16x128_f8f6f4(
                    a8[m], b8[n], acc[m][n],
                    0 /*A fmt fp8*/, 0 /*B fmt fp8*/,
                    0, 0x7F /*scaleA = 2^0*/, 0, 0x7F /*scaleB = 2^0*/);

        __syncthreads();            // reads done before next overwrite
    }

    // ---------------- epilogue ----------------
    float sum_p[16], pos_p[16], cnt_p[16];
    #pragma unroll
    for (int i = 0; i < 16; ++i) { sum_p[i] = 0.f; pos_p[i] = 0.f; cnt_p[i] = 0.f; }
    float csum[4], cpos[4], ccnt[4];
    #pragma unroll
    for (int n = 0; n < 4; ++n) { csum[n] = 0.f; cpos[n] = 0.f; ccnt[n] = 0.f; }

    if (isDiag) {
        #pragma unroll
        for (int m = 0; m < 4; ++m)
            #pragma unroll
            for (int n = 0; n < 4; ++n) {
                const int gcol = col0 + n * 16;
                #pragma unroll
                for (int r = 0; r < 4; ++r) {
                    const float s    = acc[m][n][r] * INV_T;
                    const int   i16  = m * 4 + r;
                    const int   grow = rowq + m * 16 + r;
                    const bool  diag = (grow == gcol);
                    sum_p[i16] += diag ? 0.f : __expf(s);
                    if ((labr[i16] == labc[n]) && !diag) {
                        pos_p[i16] += s; cnt_p[i16] += 1.f;
                    }
                }
            }
    } else {
        #pragma unroll
        for (int m = 0; m < 4; ++m)
            #pragma unroll
            for (int n = 0; n < 4; ++n) {
                #pragma unroll
                for (int r = 0; r < 4; ++r) {
                    const float s   = acc[m][n][r] * INV_T;
                    const int   i16 = m * 4 + r;
                    const float e   = __expf(s);
                    sum_p[i16] += e;
                    csum[n]    += e;
                    if (labr[i16] == labc[n]) {
                        pos_p[i16] += s; cnt_p[i16] += 1.f;
                        cpos[n]    += s; ccnt[n]    += 1.f;
                    }
                }
            }
    }

    // row-side: reduce across the 16 lanes sharing each row -> slice ct*2+wc
    #pragma unroll
    for (int i = 0; i < 16; ++i) {
        float se = sum_p[i], pp = pos_p[i], cc = cnt_p[i];
        #pragma unroll
        for (int off = 1; off < 16; off <<= 1) {
            se += __shfl_xor(se, off, 16);
            pp += __shfl_xor(pp, off, 16);
            cc += __shfl_xor(cc, off, 16);
        }
        if ((lane & 15) == 0) {
            const int row = rowq + (i >> 2) * 16 + (i & 3);
            const size_t idx = (size_t)row * NSLICE + ct * 2 + wc;
            psum[idx] = se;
            ppos[idx] = pp;
            pcnt[idx] = cc;
        }
    }

    // col-side (off-diag only): reduce across 4 lane-groups -> slice rt*2+wr
    if (!isDiag) {
        #pragma unroll
        for (int n = 0; n < 4; ++n) {
            float se = csum[n], pp = cpos[n], cc = ccnt[n];
            se += __shfl_xor(se, 16, 64); se += __shfl_xor(se, 32, 64);
            pp += __shfl_xor(pp, 16, 64); pp += __shfl_xor(pp, 32, 64);
            cc += __shfl_xor(cc, 16, 64); cc += __shfl_xor(cc, 32, 64);
            if (lane < 16) {
                const int gcol = col0 + n * 16;
                const size_t idx = (size_t)gcol * NSLICE + rt * 2 + wr;
                psum[idx] = se;
                ppos[idx] = pp;
                pcnt[idx] = cc;
            }
        }
    }
}

// ---------------- kernel 3a: per-row reduce over 128 slices ----------------
__global__ __launch_bounds__(128) void finalize1_kernel(
    const float* __restrict__ psum, const float* __restrict__ ppos,
    const float* __restrict__ pcnt, float* __restrict__ bpart)
{
    const int row  = blockIdx.x * 128 + threadIdx.x;
    const int lane = threadIdx.x & 63, wid = threadIdx.x >> 6;

    const float4* vs = (const float4*)(psum + (size_t)row * NSLICE);
    const float4* vp = (const float4*)(ppos + (size_t)row * NSLICE);
    const float4* vc = (const float4*)(pcnt + (size_t)row * NSLICE);
    float s = 0.f, p = 0.f, c = 0.f;
    #pragma unroll
    for (int i = 0; i < NSLICE / 4; ++i) {
        float4 a = vs[i]; s += a.x + a.y + a.z + a.w;
        float4 b = vp[i]; p += b.x + b.y + b.z + b.w;
        float4 d = vc[i]; c += d.x + d.y + d.z + d.w;
    }
    float per = (c > 0.f) ? (logf(s) - p / c) : 0.f;
    #pragma unroll
    for (int off = 32; off > 0; off >>= 1) per += __shfl_down(per, off, 64);
    __shared__ float w2[2];
    if (lane == 0) w2[wid] = per;
    __syncthreads();
    if (threadIdx.x == 0) bpart[blockIdx.x] = w2[0] + w2[1];
}

// ---------------- kernel 3b: final 64-way sum ----------------
__global__ __launch_bounds__(64) void finalize2_kernel(
    const float* __restrict__ bpart, float* __restrict__ out)
{
    const int lane = threadIdx.x;
    float v = bpart[lane];
    #pragma unroll
    for (int off = 32; off > 0; off >>= 1) v += __shfl_down(v, off, 64);
    if (lane == 0) out[0] = v;
}

extern "C" void kernel_launch(void* const* d_in, const int* in_sizes, int n_in,
                              void* d_out, int out_size, void* d_ws, size_t ws_size,
                              hipStream_t stream) {
    const float* V      = (const float*)d_in[0];
    const int*   labels = (const int*)d_in[1];
    float*       out    = (float*)d_out;

    // ws layout: A8 8 MB | psum 4 MB | ppos 4 MB | pcnt 4 MB | bpart 256 B
    unsigned char* A8 = (unsigned char*)d_ws;
    char* base = (char*)d_ws + (size_t)N_ROWS * DIM;
    float* psum  = (float*)(base);
    float* ppos  = (float*)(base + (size_t)N_ROWS * NSLICE * 4);
    float* pcnt  = (float*)(base + (size_t)N_ROWS * NSLICE * 8);
    float* bpart = (float*)(base + (size_t)N_ROWS * NSLICE * 12);

    norm_kernel<<<N_ROWS, 256, 0, stream>>>(V, A8);
    dim3 grid(NTILE, NTILE / 2 + 1);   // (64, 33), proven-locality raster
    sim_kernel<<<grid, 256, 0, stream>>>(A8, labels, psum, ppos, pcnt);
    finalize1_kernel<<<N_ROWS / 128, 128, 0, stream>>>(psum, ppos, pcnt, bpart);
    finalize2_kernel<<<1, 64, 0, stream>>>(bpart, out);
}

// Round 6
// 95.323 us; speedup vs baseline: 1.4331x; 1.0711x over previous
//
#include <hip/hip_runtime.h>
#include <hip/hip_bf16.h>
#include <stdint.h>

#define N_ROWS 8192
#define DIM    1024
#define INV_T  14.2857142857142857f   // 1/0.07

#define BM  128
#define BKB 128                  // K-bytes per LDS tile (fp8: 128 k-elements)
#define NTILE  (N_ROWS / BM)     // 64
#define NSLICE (2 * NTILE)       // 128 col-slices of 64
#define NKT    (DIM / BKB)       // 8 K-tiles

typedef int   i32x4 __attribute__((ext_vector_type(4)));
typedef int   i32x8 __attribute__((ext_vector_type(8)));
typedef float f32x4 __attribute__((ext_vector_type(4)));

// ---------------- kernel 1: row-normalize f32 -> fp8 e4m3 (OCP) ----------------
__global__ __launch_bounds__(256) void norm_kernel(
    const float* __restrict__ V, unsigned char* __restrict__ A8)
{
    const int row  = blockIdx.x;
    const int tid  = threadIdx.x;
    const int lane = tid & 63, wid = tid >> 6;

    const float4* vp = (const float4*)(V + (size_t)row * DIM);
    float4 v = vp[tid];
    float ss = v.x*v.x + v.y*v.y + v.z*v.z + v.w*v.w;
    #pragma unroll
    for (int off = 32; off > 0; off >>= 1) ss += __shfl_down(ss, off, 64);

    __shared__ float wsum[4];
    if (lane == 0) wsum[wid] = ss;
    __syncthreads();
    const float inv = 1.0f / sqrtf(wsum[0] + wsum[1] + wsum[2] + wsum[3]);

    int pk = __builtin_amdgcn_cvt_pk_fp8_f32(v.x * inv, v.y * inv, 0,  false);
    pk     = __builtin_amdgcn_cvt_pk_fp8_f32(v.z * inv, v.w * inv, pk, true);
    ((int*)(A8 + (size_t)row * DIM))[tid] = pk;
}

// ---------------- kernel 2: fused symmetric sim GEMM (MX-fp8) + epilogue ----------------
// grid (64, 33): block = unordered tile pair {rt, ct=(rt+ctl)&63}; ctl==0 diag;
// ctl==32 valid only for rt<32. Single 32KB LDS buffer, 2-phase reordered loop:
// ds_read frags -> barrier(lgkm) -> STAGE(next) -> MFMA (hides VMEM latency)
// -> barrier(vmcnt0). Partials TRANSPOSED: partial[slice][row] (contiguous
// per-block lines; kills the R5 write-amplification).
__global__ __launch_bounds__(256, 3) void sim_kernel(
    const unsigned char* __restrict__ A8, const int* __restrict__ labels,
    float* __restrict__ psum, float* __restrict__ ppos, float* __restrict__ pcnt)
{
    __shared__ __align__(16) unsigned char As[BM * BKB];   // 16 KB
    __shared__ __align__(16) unsigned char Bs[BM * BKB];   // 16 KB

    const int rt  = blockIdx.x;
    const int ctl = blockIdx.y;
    if (ctl == NTILE / 2 && rt >= NTILE / 2) return;       // uniform exit
    const int  ct     = (rt + ctl) & (NTILE - 1);
    const bool isDiag = (ctl == 0);

    const int tid  = threadIdx.x;
    const int lane = tid & 63;
    const int wid  = tid >> 6;
    const int wr   = wid >> 1;      // wave row 0..1
    const int wc   = wid & 1;       // wave col 0..1

    const int rbase = rt * BM;
    const int cbase = ct * BM;

    const int rowq = rbase + wr * 64 + ((lane >> 4) << 2);
    const int col0 = cbase + wc * 64 + (lane & 15);

    int labr[16];
    #pragma unroll
    for (int m = 0; m < 4; ++m)
        #pragma unroll
        for (int r = 0; r < 4; ++r)
            labr[m * 4 + r] = labels[rowq + m * 16 + r];
    int labc[4];
    #pragma unroll
    for (int n = 0; n < 4; ++n) labc[n] = labels[col0 + n * 16];

    f32x4 acc[4][4];
    #pragma unroll
    for (int m = 0; m < 4; ++m)
        #pragma unroll
        for (int n = 0; n < 4; ++n)
            acc[m][n] = (f32x4){0.f, 0.f, 0.f, 0.f};

    // staging: linear LDS dest; source 16B-chunk XOR-swizzled (^row&7), read
    // side applies the same XOR (rule 21 involution pair).
    #define STAGE(kt)                                                              \
    {                                                                              \
        const int kbase = (kt) * BKB;                                              \
        _Pragma("unroll")                                                          \
        for (int i = 0; i < 4; ++i) {                                              \
            const int c    = i * 256 + tid;                                        \
            const int rowc = c >> 3;                                               \
            const int kcs  = (c & 7) ^ (rowc & 7);                                 \
            const unsigned char* gA = A8 + (size_t)(rbase + rowc) * DIM + kbase + kcs * 16; \
            const unsigned char* gB = A8 + (size_t)(cbase + rowc) * DIM + kbase + kcs * 16; \
            const int ldsOff = i * 4096 + wid * 1024;   /* +lane*16 by HW */       \
            __builtin_amdgcn_global_load_lds(                                      \
                (const __attribute__((address_space(1))) void*)gA,                 \
                (__attribute__((address_space(3))) void*)(As + ldsOff),            \
                16, 0, 0);                                                         \
            __builtin_amdgcn_global_load_lds(                                      \
                (const __attribute__((address_space(1))) void*)gB,                 \
                (__attribute__((address_space(3))) void*)(Bs + ldsOff),            \
                16, 0, 0);                                                         \
        }                                                                          \
    }

    const int t = lane >> 4;        // K-block 0..3 (32 k-bytes each)

    STAGE(0);
    __syncthreads();                // tile 0 resident

    for (int kt = 0; kt < NKT; ++kt) {
        // ---- phase A: pull all fragments of tile kt into registers
        i32x8 a8[4], b8[4];
        #pragma unroll
        for (int m = 0; m < 4; ++m) {
            const int rowa = wr * 64 + m * 16 + (lane & 15);
            const int c0 = ((2 * t)     ^ (rowa & 7)) << 4;
            const int c1 = ((2 * t + 1) ^ (rowa & 7)) << 4;
            i32x4 lo = *(const i32x4*)(As + rowa * BKB + c0);
            i32x4 hi = *(const i32x4*)(As + rowa * BKB + c1);
            i32x8 f; f[0]=lo[0]; f[1]=lo[1]; f[2]=lo[2]; f[3]=lo[3];
                     f[4]=hi[0]; f[5]=hi[1]; f[6]=hi[2]; f[7]=hi[3];
            a8[m] = f;
        }
        #pragma unroll
        for (int n = 0; n < 4; ++n) {
            const int rowb = wc * 64 + n * 16 + (lane & 15);
            const int c0 = ((2 * t)     ^ (rowb & 7)) << 4;
            const int c1 = ((2 * t + 1) ^ (rowb & 7)) << 4;
            i32x4 lo = *(const i32x4*)(Bs + rowb * BKB + c0);
            i32x4 hi = *(const i32x4*)(Bs + rowb * BKB + c1);
            i32x8 f; f[0]=lo[0]; f[1]=lo[1]; f[2]=lo[2]; f[3]=lo[3];
                     f[4]=hi[0]; f[5]=hi[1]; f[6]=hi[2]; f[7]=hi[3];
            b8[n] = f;
        }
        __syncthreads();            // lgkm(0): all waves' LDS reads complete
                                    // (vmcnt already 0 from previous iteration)

        // ---- phase B: refill LDS for kt+1 while MFMAs run from registers
        if (kt + 1 < NKT) STAGE(kt + 1);

        __builtin_amdgcn_s_setprio(1);
        #pragma unroll
        for (int m = 0; m < 4; ++m)
            #pragma unroll
            for (int n = 0; n < 4; ++n)
                acc[m][n] = __builtin_amdgcn_mfma_scale_f32_16x16x128_f8f6f4(
                    a8[m], b8[n], acc[m][n],
                    0 /*A fmt fp8*/, 0 /*B fmt fp8*/,
                    0, 0x7F /*scaleA = 2^0*/, 0, 0x7F /*scaleB = 2^0*/);
        __builtin_amdgcn_s_setprio(0);

        __syncthreads();            // drains vmcnt(0): tile kt+1 resident
    }

    // ---------------- epilogue ----------------
    float sum_p[16], pos_p[16], cnt_p[16];
    #pragma unroll
    for (int i = 0; i < 16; ++i) { sum_p[i] = 0.f; pos_p[i] = 0.f; cnt_p[i] = 0.f; }
    float csum[4], cpos[4], ccnt[4];
    #pragma unroll
    for (int n = 0; n < 4; ++n) { csum[n] = 0.f; cpos[n] = 0.f; ccnt[n] = 0.f; }

    if (isDiag) {
        #pragma unroll
        for (int m = 0; m < 4; ++m)
            #pragma unroll
            for (int n = 0; n < 4; ++n) {
                const int gcol = col0 + n * 16;
                #pragma unroll
                for (int r = 0; r < 4; ++r) {
                    const float s    = acc[m][n][r] * INV_T;
                    const int   i16  = m * 4 + r;
                    const int   grow = rowq + m * 16 + r;
                    const bool  diag = (grow == gcol);
                    sum_p[i16] += diag ? 0.f : __expf(s);
                    if ((labr[i16] == labc[n]) && !diag) {
                        pos_p[i16] += s; cnt_p[i16] += 1.f;
                    }
                }
            }
    } else {
        #pragma unroll
        for (int m = 0; m < 4; ++m)
            #pragma unroll
            for (int n = 0; n < 4; ++n) {
                #pragma unroll
                for (int r = 0; r < 4; ++r) {
                    const float s   = acc[m][n][r] * INV_T;
                    const int   i16 = m * 4 + r;
                    const float e   = __expf(s);
                    sum_p[i16] += e;
                    csum[n]    += e;
                    if (labr[i16] == labc[n]) {
                        pos_p[i16] += s; cnt_p[i16] += 1.f;
                        cpos[n]    += s; ccnt[n]    += 1.f;
                    }
                }
            }
    }

    // row-side: reduce across 16 lanes sharing each row -> partial[ct*2+wc][row]
    #pragma unroll
    for (int i = 0; i < 16; ++i) {
        float se = sum_p[i], pp = pos_p[i], cc = cnt_p[i];
        #pragma unroll
        for (int off = 1; off < 16; off <<= 1) {
            se += __shfl_xor(se, off, 16);
            pp += __shfl_xor(pp, off, 16);
            cc += __shfl_xor(cc, off, 16);
        }
        if ((lane & 15) == 0) {
            const int row = rowq + (i >> 2) * 16 + (i & 3);
            const size_t idx = (size_t)(ct * 2 + wc) * N_ROWS + row;
            psum[idx] = se;
            ppos[idx] = pp;
            pcnt[idx] = cc;
        }
    }

    // col-side (off-diag only): reduce across 4 lane-groups -> partial[rt*2+wr][col]
    if (!isDiag) {
        #pragma unroll
        for (int n = 0; n < 4; ++n) {
            float se = csum[n], pp = cpos[n], cc = ccnt[n];
            se += __shfl_xor(se, 16, 64); se += __shfl_xor(se, 32, 64);
            pp += __shfl_xor(pp, 16, 64); pp += __shfl_xor(pp, 32, 64);
            cc += __shfl_xor(cc, 16, 64); cc += __shfl_xor(cc, 32, 64);
            if (lane < 16) {
                const int gcol = col0 + n * 16;
                const size_t idx = (size_t)(rt * 2 + wr) * N_ROWS + gcol;
                psum[idx] = se;
                ppos[idx] = pp;
                pcnt[idx] = cc;
            }
        }
    }
}

// ---------------- kernel 3: fused finalize (per-row logsumexp + global sum) ----
// partial[slice][row]: for fixed slice, consecutive rows -> coalesced reads.
__global__ __launch_bounds__(256) void finalize_kernel(
    const float* __restrict__ psum, const float* __restrict__ ppos,
    const float* __restrict__ pcnt, float* __restrict__ out)
{
    const int row  = blockIdx.x * 256 + threadIdx.x;
    const int lane = threadIdx.x & 63, wid = threadIdx.x >> 6;

    float s = 0.f, p = 0.f, c = 0.f;
    #pragma unroll 8
    for (int sl = 0; sl < NSLICE; ++sl) {
        const size_t idx = (size_t)sl * N_ROWS + row;
        s += psum[idx];
        p += ppos[idx];
        c += pcnt[idx];
    }
    float per = (c > 0.f) ? (logf(s) - p / c) : 0.f;
    #pragma unroll
    for (int off = 32; off > 0; off >>= 1) per += __shfl_down(per, off, 64);
    __shared__ float w4[4];
    if (lane == 0) w4[wid] = per;
    __syncthreads();
    if (threadIdx.x == 0)
        atomicAdd(out, w4[0] + w4[1] + w4[2] + w4[3]);
}

extern "C" void kernel_launch(void* const* d_in, const int* in_sizes, int n_in,
                              void* d_out, int out_size, void* d_ws, size_t ws_size,
                              hipStream_t stream) {
    const float* V      = (const float*)d_in[0];
    const int*   labels = (const int*)d_in[1];
    float*       out    = (float*)d_out;

    // ws layout: A8 8 MB | psum 4 MB | ppos 4 MB | pcnt 4 MB
    unsigned char* A8 = (unsigned char*)d_ws;
    char* base = (char*)d_ws + (size_t)N_ROWS * DIM;
    float* psum = (float*)(base);
    float* ppos = (float*)(base + (size_t)NSLICE * N_ROWS * 4);
    float* pcnt = (float*)(base + (size_t)NSLICE * N_ROWS * 8);

    hipMemsetAsync(out, 0, sizeof(float), stream);
    norm_kernel<<<N_ROWS, 256, 0, stream>>>(V, A8);
    dim3 grid(NTILE, NTILE / 2 + 1);   // (64, 33), proven-locality raster
    sim_kernel<<<grid, 256, 0, stream>>>(A8, labels, psum, ppos, pcnt);
    finalize_kernel<<<N_ROWS / 256, 256, 0, stream>>>(psum, ppos, pcnt, out);
}

// Round 7
// 89.843 us; speedup vs baseline: 1.5205x; 1.0610x over previous
//
#include <hip/hip_runtime.h>
#include <hip/hip_bf16.h>
#include <stdint.h>

#define N_ROWS 8192
#define DIM    1024
#define INV_T  14.2857142857142857f   // 1/0.07

#define BM  128
#define BKB 128                  // K-bytes per LDS tile (fp8: 128 k-elements)
#define NTILE  (N_ROWS / BM)     // 64
#define NSLICE (2 * NTILE)       // 128 col-slices of 64
#define NKT    (DIM / BKB)       // 8 K-tiles
#define NPAIR  2080              // 64 diag + 64*63/2 off-diag
#define PER_XCD (NPAIR / 8)      // 260

typedef int   i32x4 __attribute__((ext_vector_type(4)));
typedef int   i32x8 __attribute__((ext_vector_type(8)));
typedef float f32x4 __attribute__((ext_vector_type(4)));

// ---------------- kernel 1: row-normalize f32 -> fp8 e4m3 (OCP) ----------------
__global__ __launch_bounds__(256) void norm_kernel(
    const float* __restrict__ V, unsigned char* __restrict__ A8)
{
    const int row  = blockIdx.x;
    const int tid  = threadIdx.x;
    const int lane = tid & 63, wid = tid >> 6;

    const float4* vp = (const float4*)(V + (size_t)row * DIM);
    float4 v = vp[tid];
    float ss = v.x*v.x + v.y*v.y + v.z*v.z + v.w*v.w;
    #pragma unroll
    for (int off = 32; off > 0; off >>= 1) ss += __shfl_down(ss, off, 64);

    __shared__ float wsum[4];
    if (lane == 0) wsum[wid] = ss;
    __syncthreads();
    const float inv = 1.0f / sqrtf(wsum[0] + wsum[1] + wsum[2] + wsum[3]);

    int pk = __builtin_amdgcn_cvt_pk_fp8_f32(v.x * inv, v.y * inv, 0,  false);
    pk     = __builtin_amdgcn_cvt_pk_fp8_f32(v.z * inv, v.w * inv, pk, true);
    ((int*)(A8 + (size_t)row * DIM))[tid] = pk;
}

// ---------------- kernel 2: fused symmetric sim GEMM (MX-fp8) + epilogue ----------------
// 1-D grid of exactly 2080 pair-blocks. Supertile decomposition: the 64x64
// tile-pair space is grouped into 8x8-tile supertiles (36 upper-tri STs;
// diag ST = 36 pairs, off-diag = 64). Supertiles are linearized row-major
// (RT band outer, CT inner => A-band panels persist), and blockIdx is mapped
// so XCD k = b%8 executes the contiguous pair range [k*260, (k+1)*260):
// per-XCD concurrent working set ~2-3 MB < 4 MB L2 (vs ~8 MB thrash before).
// Shell unchanged from R6: single 32KB LDS buffer, 2-phase reorder, fp8-MX
// MFMA (scale 0x7F = 1.0), transposed partials [slice][row].
__global__ __launch_bounds__(256, 3) void sim_kernel(
    const unsigned char* __restrict__ A8, const int* __restrict__ labels,
    float* __restrict__ psum, float* __restrict__ ppos, float* __restrict__ pcnt)
{
    __shared__ __align__(16) unsigned char As[BM * BKB];   // 16 KB
    __shared__ __align__(16) unsigned char Bs[BM * BKB];   // 16 KB

    // ---- supertile pair decode (uniform per block, scalar) ----
    const int b = blockIdx.x;                    // 0..2079
    const int v = (b & 7) * PER_XCD + (b >> 3);  // XCD-contiguous virtual index
    int rem = v, RT = 0, rowsz = 36 + 7 * 64;    // ST-row RT size
    while (rem >= rowsz) { rem -= rowsz; ++RT; rowsz -= 64; }
    int rt, ct;
    if (rem < 36) {                              // diagonal supertile
        int i = 0, left = 8;
        while (rem >= left) { rem -= left; ++i; --left; }
        rt = RT * 8 + i;  ct = RT * 8 + i + rem;
    } else {                                     // off-diagonal supertile
        const int o  = rem - 36;
        const int CT = RT + 1 + (o >> 6);
        const int w  = o & 63;
        rt = RT * 8 + (w >> 3);
        ct = CT * 8 + (w & 7);
    }
    const bool isDiag = (rt == ct);

    const int tid  = threadIdx.x;
    const int lane = tid & 63;
    const int wid  = tid >> 6;
    const int wr   = wid >> 1;      // wave row 0..1
    const int wc   = wid & 1;       // wave col 0..1

    const int rbase = rt * BM;
    const int cbase = ct * BM;

    const int rowq = rbase + wr * 64 + ((lane >> 4) << 2);
    const int col0 = cbase + wc * 64 + (lane & 15);

    int labr[16];
    #pragma unroll
    for (int m = 0; m < 4; ++m)
        #pragma unroll
        for (int r = 0; r < 4; ++r)
            labr[m * 4 + r] = labels[rowq + m * 16 + r];
    int labc[4];
    #pragma unroll
    for (int n = 0; n < 4; ++n) labc[n] = labels[col0 + n * 16];

    f32x4 acc[4][4];
    #pragma unroll
    for (int m = 0; m < 4; ++m)
        #pragma unroll
        for (int n = 0; n < 4; ++n)
            acc[m][n] = (f32x4){0.f, 0.f, 0.f, 0.f};

    // staging: linear LDS dest; source 16B-chunk XOR-swizzled (^row&7), read
    // side applies the same XOR (rule 21 involution pair).
    #define STAGE(kt)                                                              \
    {                                                                              \
        const int kbase = (kt) * BKB;                                              \
        _Pragma("unroll")                                                          \
        for (int i = 0; i < 4; ++i) {                                              \
            const int c    = i * 256 + tid;                                        \
            const int rowc = c >> 3;                                               \
            const int kcs  = (c & 7) ^ (rowc & 7);                                 \
            const unsigned char* gA = A8 + (size_t)(rbase + rowc) * DIM + kbase + kcs * 16; \
            const unsigned char* gB = A8 + (size_t)(cbase + rowc) * DIM + kbase + kcs * 16; \
            const int ldsOff = i * 4096 + wid * 1024;   /* +lane*16 by HW */       \
            __builtin_amdgcn_global_load_lds(                                      \
                (const __attribute__((address_space(1))) void*)gA,                 \
                (__attribute__((address_space(3))) void*)(As + ldsOff),            \
                16, 0, 0);                                                         \
            __builtin_amdgcn_global_load_lds(                                      \
                (const __attribute__((address_space(1))) void*)gB,                 \
                (__attribute__((address_space(3))) void*)(Bs + ldsOff),            \
                16, 0, 0);                                                         \
        }                                                                          \
    }

    const int t = lane >> 4;        // K-block 0..3 (32 k-bytes each)

    STAGE(0);
    __syncthreads();                // tile 0 resident

    for (int kt = 0; kt < NKT; ++kt) {
        // ---- phase A: pull all fragments of tile kt into registers
        i32x8 a8[4], b8[4];
        #pragma unroll
        for (int m = 0; m < 4; ++m) {
            const int rowa = wr * 64 + m * 16 + (lane & 15);
            const int c0 = ((2 * t)     ^ (rowa & 7)) << 4;
            const int c1 = ((2 * t + 1) ^ (rowa & 7)) << 4;
            i32x4 lo = *(const i32x4*)(As + rowa * BKB + c0);
            i32x4 hi = *(const i32x4*)(As + rowa * BKB + c1);
            i32x8 f; f[0]=lo[0]; f[1]=lo[1]; f[2]=lo[2]; f[3]=lo[3];
                     f[4]=hi[0]; f[5]=hi[1]; f[6]=hi[2]; f[7]=hi[3];
            a8[m] = f;
        }
        #pragma unroll
        for (int n = 0; n < 4; ++n) {
            const int rowb = wc * 64 + n * 16 + (lane & 15);
            const int c0 = ((2 * t)     ^ (rowb & 7)) << 4;
            const int c1 = ((2 * t + 1) ^ (rowb & 7)) << 4;
            i32x4 lo = *(const i32x4*)(Bs + rowb * BKB + c0);
            i32x4 hi = *(const i32x4*)(Bs + rowb * BKB + c1);
            i32x8 f; f[0]=lo[0]; f[1]=lo[1]; f[2]=lo[2]; f[3]=lo[3];
                     f[4]=hi[0]; f[5]=hi[1]; f[6]=hi[2]; f[7]=hi[3];
            b8[n] = f;
        }
        __syncthreads();            // lgkm(0): all waves' LDS reads complete
                                    // (vmcnt already 0 from previous iteration)

        // ---- phase B: refill LDS for kt+1 while MFMAs run from registers
        if (kt + 1 < NKT) STAGE(kt + 1);

        __builtin_amdgcn_s_setprio(1);
        #pragma unroll
        for (int m = 0; m < 4; ++m)
            #pragma unroll
            for (int n = 0; n < 4; ++n)
                acc[m][n] = __builtin_amdgcn_mfma_scale_f32_16x16x128_f8f6f4(
                    a8[m], b8[n], acc[m][n],
                    0 /*A fmt fp8*/, 0 /*B fmt fp8*/,
                    0, 0x7F /*scaleA = 2^0*/, 0, 0x7F /*scaleB = 2^0*/);
        __builtin_amdgcn_s_setprio(0);

        __syncthreads();            // drains vmcnt(0): tile kt+1 resident
    }

    // ---------------- epilogue ----------------
    float sum_p[16], pos_p[16], cnt_p[16];
    #pragma unroll
    for (int i = 0; i < 16; ++i) { sum_p[i] = 0.f; pos_p[i] = 0.f; cnt_p[i] = 0.f; }
    float csum[4], cpos[4], ccnt[4];
    #pragma unroll
    for (int n = 0; n < 4; ++n) { csum[n] = 0.f; cpos[n] = 0.f; ccnt[n] = 0.f; }

    if (isDiag) {
        #pragma unroll
        for (int m = 0; m < 4; ++m)
            #pragma unroll
            for (int n = 0; n < 4; ++n) {
                const int gcol = col0 + n * 16;
                #pragma unroll
                for (int r = 0; r < 4; ++r) {
                    const float s    = acc[m][n][r] * INV_T;
                    const int   i16  = m * 4 + r;
                    const int   grow = rowq + m * 16 + r;
                    const bool  diag = (grow == gcol);
                    sum_p[i16] += diag ? 0.f : __expf(s);
                    if ((labr[i16] == labc[n]) && !diag) {
                        pos_p[i16] += s; cnt_p[i16] += 1.f;
                    }
                }
            }
    } else {
        #pragma unroll
        for (int m = 0; m < 4; ++m)
            #pragma unroll
            for (int n = 0; n < 4; ++n) {
                #pragma unroll
                for (int r = 0; r < 4; ++r) {
                    const float s   = acc[m][n][r] * INV_T;
                    const int   i16 = m * 4 + r;
                    const float e   = __expf(s);
                    sum_p[i16] += e;
                    csum[n]    += e;
                    if (labr[i16] == labc[n]) {
                        pos_p[i16] += s; cnt_p[i16] += 1.f;
                        cpos[n]    += s; ccnt[n]    += 1.f;
                    }
                }
            }
    }

    // row-side: reduce across 16 lanes sharing each row -> partial[ct*2+wc][row]
    #pragma unroll
    for (int i = 0; i < 16; ++i) {
        float se = sum_p[i], pp = pos_p[i], cc = cnt_p[i];
        #pragma unroll
        for (int off = 1; off < 16; off <<= 1) {
            se += __shfl_xor(se, off, 16);
            pp += __shfl_xor(pp, off, 16);
            cc += __shfl_xor(cc, off, 16);
        }
        if ((lane & 15) == 0) {
            const int row = rowq + (i >> 2) * 16 + (i & 3);
            const size_t idx = (size_t)(ct * 2 + wc) * N_ROWS + row;
            psum[idx] = se;
            ppos[idx] = pp;
            pcnt[idx] = cc;
        }
    }

    // col-side (off-diag only): reduce across 4 lane-groups -> partial[rt*2+wr][col]
    if (!isDiag) {
        #pragma unroll
        for (int n = 0; n < 4; ++n) {
            float se = csum[n], pp = cpos[n], cc = ccnt[n];
            se += __shfl_xor(se, 16, 64); se += __shfl_xor(se, 32, 64);
            pp += __shfl_xor(pp, 16, 64); pp += __shfl_xor(pp, 32, 64);
            cc += __shfl_xor(cc, 16, 64); cc += __shfl_xor(cc, 32, 64);
            if (lane < 16) {
                const int gcol = col0 + n * 16;
                const size_t idx = (size_t)(rt * 2 + wr) * N_ROWS + gcol;
                psum[idx] = se;
                ppos[idx] = pp;
                pcnt[idx] = cc;
            }
        }
    }
}

// ---------------- kernel 3: fused finalize (per-row logsumexp + global sum) ----
__global__ __launch_bounds__(256) void finalize_kernel(
    const float* __restrict__ psum, const float* __restrict__ ppos,
    const float* __restrict__ pcnt, float* __restrict__ out)
{
    const int row  = blockIdx.x * 256 + threadIdx.x;
    const int lane = threadIdx.x & 63, wid = threadIdx.x >> 6;

    float s = 0.f, p = 0.f, c = 0.f;
    #pragma unroll 8
    for (int sl = 0; sl < NSLICE; ++sl) {
        const size_t idx = (size_t)sl * N_ROWS + row;
        s += psum[idx];
        p += ppos[idx];
        c += pcnt[idx];
    }
    float per = (c > 0.f) ? (logf(s) - p / c) : 0.f;
    #pragma unroll
    for (int off = 32; off > 0; off >>= 1) per += __shfl_down(per, off, 64);
    __shared__ float w4[4];
    if (lane == 0) w4[wid] = per;
    __syncthreads();
    if (threadIdx.x == 0)
        atomicAdd(out, w4[0] + w4[1] + w4[2] + w4[3]);
}

extern "C" void kernel_launch(void* const* d_in, const int* in_sizes, int n_in,
                              void* d_out, int out_size, void* d_ws, size_t ws_size,
                              hipStream_t stream) {
    const float* V      = (const float*)d_in[0];
    const int*   labels = (const int*)d_in[1];
    float*       out    = (float*)d_out;

    // ws layout: A8 8 MB | psum 4 MB | ppos 4 MB | pcnt 4 MB
    unsigned char* A8 = (unsigned char*)d_ws;
    char* base = (char*)d_ws + (size_t)N_ROWS * DIM;
    float* psum = (float*)(base);
    float* ppos = (float*)(base + (size_t)NSLICE * N_ROWS * 4);
    float* pcnt = (float*)(base + (size_t)NSLICE * N_ROWS * 8);

    hipMemsetAsync(out, 0, sizeof(float), stream);
    norm_kernel<<<N_ROWS, 256, 0, stream>>>(V, A8);
    sim_kernel<<<NPAIR, 256, 0, stream>>>(A8, labels, psum, ppos, pcnt);
    finalize_kernel<<<N_ROWS / 256, 256, 0, stream>>>(psum, ppos, pcnt, out);
}